// Round 7
// baseline (73.084 us; speedup 1.0000x reference)
//
#include <hip/hip_runtime.h>

#define PH 7
#define PW 7
#define SCALE 0.0625f
#define C_TOTAL 1024
#define H_ 50
#define W_ 50
#define HW_TOTAL (H_ * W_)                  // 2500
#define NROIS 512
#define NBIN (PH * PW)                      // 49
#define CHB 128                             // channels per block (float2 per lane)
#define NCHUNK (C_TOTAL / CHB)              // 8
#define ROWB (W_ * C_TOTAL * 4)             // featT row stride bytes (204800)
#define COLB (C_TOTAL * 4)                  // featT col stride bytes (4096)
#define RMAX 17                             // max distinct rows per ROI (bh<=16/7 -> R<=17, clamped)
#define GP   130                            // padded channel pitch of s_G (even -> 8B-aligned float2;
                                            // 130%32=2 spreads phase-2 banks)

// ---------------- transpose: feat [C, HW] -> featT [HW, C] ----------------
__global__ __launch_bounds__(256) void transpose_kernel(
    const float* __restrict__ feat, float* __restrict__ featT)
{
    __shared__ float tile[64][65];
    const int hw0 = (blockIdx.x % 40) * 64;
    const int c0  = (blockIdx.x / 40) * 64;
    const int tx = threadIdx.x & 63;
    const int ty = threadIdx.x >> 6;        // 0..3

    const int hw_r = hw0 + tx;
    if (hw_r < HW_TOTAL) {
        #pragma unroll
        for (int j = 0; j < 16; ++j) {
            const int c_l = j * 4 + ty;
            tile[c_l][tx] = feat[(size_t)(c0 + c_l) * HW_TOTAL + hw_r];
        }
    }
    __syncthreads();
    #pragma unroll
    for (int j = 0; j < 16; ++j) {
        const int hw_l = j * 4 + ty;
        const int hw = hw0 + hw_l;
        if (hw < HW_TOTAL)
            featT[(size_t)hw * C_TOTAL + c0 + tx] = tile[tx][hw_l];
    }
}

// uniform SGPR base + VGPR byte offset -> saddr+voffset global_load_dwordx2
__device__ __forceinline__ float2 ldf2(const char* base, unsigned byte_off) {
    return *reinterpret_cast<const float2*>(base + byte_off);
}

// ---------------- main: separable two-phase ROI-align ----------------
// out[py][px] = sum_j WY_j * G[row_j][px],  G[r][px] = sum_i WX_i * F[r, x_i]
// R7: CHB 64->128 via dwordx2 taps (512 B/instr). Evidence from R3/R4/R6:
// binder is EXPOSED LOAD LATENCY (R6 cut bytes 33% at shallow MLP -> no
// change vs R3; only R4's deep straight-line batch helped). Halving the
// grid (4096 blocks) at constant per-block critical path halves the
// per-CU sequential block count; in-flight bytes/CU rise 172->229 KB.
// (512,4) -> 128-VGPR cap so the 56-VGPR float2 batch stays live
// (R3/R6 collapse tripwire: VGPR_Count must be >=90, not 20).
__global__ __launch_bounds__(512, 4) void roi_sep_kernel(
    const float* __restrict__ featT,
    const float* __restrict__ rois,
    float* __restrict__ out)
{
    __shared__ __align__(16) float s_G[RMAX * 7 * GP];  // 61880 B [slot][px][ch(pad130)]
    __shared__ __align__(16) int   s_xoff[7][4];        // col byte offsets (compacted)
    __shared__ __align__(16) float s_xw[7][4];
    __shared__ __align__(16) int   s_yiT[4][NBIN];      // transposed: elem index into s_G
    __shared__ __align__(16) float s_ywT[4][NBIN];      // transposed: y-tap weights

    const int blk    = blockIdx.x;
    const int roi_id = blk >> 3;             // / NCHUNK
    const int chunk  = blk & (NCHUNK - 1);
    const int tid    = threadIdx.x;

    const float* roi = rois + roi_id * 5;

    // row range (uniform scalar math, recomputed identically by all threads)
    const float shy = roi[2] * SCALE, ehy = roi[4] * SCALE;
    const float rht = fmaxf(ehy - shy, 1.0f);
    const float bh  = rht * (1.0f / 7.0f);
    int r0 = (int)floorf(fmaxf(shy + 0.25f * bh, 0.0f));
    if (r0 > H_ - 1) r0 = H_ - 1;
    const int lol = (int)floorf(fmaxf(shy + 6.75f * bh, 0.0f));
    int r1 = (lol >= H_ - 1) ? (H_ - 1) : (lol + 1);
    if (r1 - r0 + 1 > RMAX) r1 = r0 + RMAX - 1;   // corruption guard (never fires: bh<=16/7)
    const int R  = r1 - r0 + 1;              // <= 17

    // ---- x tables: 7 threads, merge+compact 2 samples -> 4 padded slots ----
    if (tid < 7) {
        const float swx = roi[1] * SCALE, ewx = roi[3] * SCALE;
        const float rwd = fmaxf(ewx - swx, 1.0f);
        const float bw  = rwd * (1.0f / 7.0f);
        const float base = swx + (float)tid * bw;
        const float v0 = base + 0.25f * bw;
        const float v1 = base + 0.75f * bw;

        int lo0, hi0, lo1, hi1;
        float l0, h0, l1, h1, m0, m1;
        {
            const bool val = (v0 >= -1.0f) && (v0 <= (float)W_);
            float vc = fmaxf(v0, 0.0f);
            int lo = (int)floorf(vc);
            if (lo >= W_ - 1) { lo0 = W_ - 1; hi0 = W_ - 1; vc = (float)(W_ - 1); }
            else              { lo0 = lo; hi0 = lo + 1; }
            l0 = vc - (float)lo0; h0 = 1.0f - l0;
            m0 = val ? 1.0f : 0.0f;
        }
        {
            const bool val = (v1 >= -1.0f) && (v1 <= (float)W_);
            float vc = fmaxf(v1, 0.0f);
            int lo = (int)floorf(vc);
            if (lo >= W_ - 1) { lo1 = W_ - 1; hi1 = W_ - 1; vc = (float)(W_ - 1); }
            else              { lo1 = lo; hi1 = lo + 1; }
            l1 = vc - (float)lo1; h1 = 1.0f - l1;
            m1 = val ? 1.0f : 0.0f;
        }

        float W0 = h0 * m0, W1 = l0 * m0, W2 = h1 * m1, W3 = l1 * m1;
        int I0 = lo0, I1 = hi0, I2 = lo1, I3 = hi1;
        if (I1 == I0) { W0 += W1; W1 = 0.0f; }
        if (I2 == I0) { W0 += W2; W2 = 0.0f; }
        else if (I2 == I1) { W1 += W2; W2 = 0.0f; }
        if (I3 == I0) { W0 += W3; W3 = 0.0f; }
        else if (I3 == I1) { W1 += W3; W3 = 0.0f; }
        else if (I3 == I2) { W2 += W3; W3 = 0.0f; }

        // compact zeros right (static swaps). Padded slots keep real in-range
        // indices (duplicates of live entries) with weight 0 -> same-line loads.
        #define CSH(A, B) if (W##A == 0.0f && W##B != 0.0f) { W##A = W##B; I##A = I##B; W##B = 0.0f; }
        CSH(0,1) CSH(1,2) CSH(2,3)
        CSH(0,1) CSH(1,2) CSH(2,3)
        CSH(0,1) CSH(1,2) CSH(2,3)
        #undef CSH

        s_xoff[tid][0] = I0 * COLB; s_xoff[tid][1] = I1 * COLB;
        s_xoff[tid][2] = I2 * COLB; s_xoff[tid][3] = I3 * COLB;
        s_xw[tid][0] = W0; s_xw[tid][1] = W1; s_xw[tid][2] = W2; s_xw[tid][3] = W3;
    }

    // ---- y tables: 49 threads (tid 64..112), one per bin ----
    if (tid >= 64 && tid < 64 + NBIN) {
        const int bin = tid - 64;
        const int py  = bin / 7, px = bin - py * 7;
        const float base = shy + (float)py * bh;
        const float v0 = base + 0.25f * bh;
        const float v1 = base + 0.75f * bh;

        int lo0, hi0, lo1, hi1;
        float l0, h0, l1, h1, m0, m1;
        {
            const bool val = (v0 >= -1.0f) && (v0 <= (float)H_);
            float vc = fmaxf(v0, 0.0f);
            int lo = (int)floorf(vc);
            if (lo >= H_ - 1) { lo0 = H_ - 1; hi0 = H_ - 1; vc = (float)(H_ - 1); }
            else              { lo0 = lo; hi0 = lo + 1; }
            l0 = vc - (float)lo0; h0 = 1.0f - l0;
            m0 = val ? 0.25f : 0.0f;                     // fold mask + /4 mean
        }
        {
            const bool val = (v1 >= -1.0f) && (v1 <= (float)H_);
            float vc = fmaxf(v1, 0.0f);
            int lo = (int)floorf(vc);
            if (lo >= H_ - 1) { lo1 = H_ - 1; hi1 = H_ - 1; vc = (float)(H_ - 1); }
            else              { lo1 = lo; hi1 = lo + 1; }
            l1 = vc - (float)lo1; h1 = 1.0f - l1;
            m1 = val ? 0.25f : 0.0f;
        }

        // slot clamp matches the (never-firing) R clamp above
        const int s0 = min(lo0 - r0, RMAX - 1), s1 = min(hi0 - r0, RMAX - 1);
        const int s2 = min(lo1 - r0, RMAX - 1), s3 = min(hi1 - r0, RMAX - 1);
        s_yiT[0][bin] = (s0 * 7 + px) * GP;
        s_yiT[1][bin] = (s1 * 7 + px) * GP;
        s_yiT[2][bin] = (s2 * 7 + px) * GP;
        s_yiT[3][bin] = (s3 * 7 + px) * GP;
        s_ywT[0][bin] = h0 * m0; s_ywT[1][bin] = l0 * m0;
        s_ywT[2][bin] = h1 * m1; s_ywT[3][bin] = l1 * m1;
    }
    __syncthreads();

    // ---- hoist x tables into SGPRs (wave-uniform; 0 VGPR cost) ----
    int   xo_s[7][4];
    float xw_s[7][4];
    #pragma unroll
    for (int i = 0; i < 7; ++i) {
        const int4   t = *(const int4*)  s_xoff[i];
        const float4 w = *(const float4*)s_xw[i];
        xo_s[i][0] = __builtin_amdgcn_readfirstlane(t.x);
        xo_s[i][1] = __builtin_amdgcn_readfirstlane(t.y);
        xo_s[i][2] = __builtin_amdgcn_readfirstlane(t.z);
        xo_s[i][3] = __builtin_amdgcn_readfirstlane(t.w);
        xw_s[i][0] = __uint_as_float(__builtin_amdgcn_readfirstlane(__float_as_uint(w.x)));
        xw_s[i][1] = __uint_as_float(__builtin_amdgcn_readfirstlane(__float_as_uint(w.y)));
        xw_s[i][2] = __uint_as_float(__builtin_amdgcn_readfirstlane(__float_as_uint(w.z)));
        xw_s[i][3] = __uint_as_float(__builtin_amdgcn_readfirstlane(__float_as_uint(w.w)));
    }

    // ---- phase 1: G[row][px][ch] -- row-based, 28 batched dwordx2 loads ----
    // lane covers channels (2*lane, 2*lane+1); 512 B/instruction.
    const int wave = tid >> 6, lane = tid & 63;
    const char* fb  = (const char*)featT;
    const int laneB = (chunk * CHB + lane * 2) * 4;

    for (int rs = wave; rs < R; rs += 8) {
        const unsigned rb = (unsigned)(laneB + (r0 + rs) * ROWB);
        float2 f[7][4];
        #pragma unroll
        for (int px = 0; px < 7; ++px) {
            f[px][0] = ldf2(fb + xo_s[px][0], rb);
            f[px][1] = ldf2(fb + xo_s[px][1], rb);
            f[px][2] = ldf2(fb + xo_s[px][2], rb);
            f[px][3] = ldf2(fb + xo_s[px][3], rb);
        }
        // fence: compiler may not sink loads below this point -> all 28 issue
        // before the first use (28-deep MLP, 512 B each)
        __asm__ __volatile__("" ::: "memory");
        float* gbase = &s_G[rs * 7 * GP + lane * 2];
        #pragma unroll
        for (int px = 0; px < 7; ++px) {
            float2 g;
            g.x = (xw_s[px][0] * f[px][0].x + xw_s[px][1] * f[px][1].x)
                + (xw_s[px][2] * f[px][2].x + xw_s[px][3] * f[px][3].x);
            g.y = (xw_s[px][0] * f[px][0].y + xw_s[px][1] * f[px][1].y)
                + (xw_s[px][2] * f[px][2].y + xw_s[px][3] * f[px][3].y);
            *reinterpret_cast<float2*>(&gbase[px * GP]) = g;   // GP even -> 8B aligned
        }
    }
    __syncthreads();

    // ---- phase 2 (fused store): thread handles o and o+3136 (same bin,
    // channels c and c+64) -> table reads + index math amortized over 2
    // outputs; stores stay lane-linear (o IS the linear output index).
    float* obase = out + (size_t)roi_id * (C_TOTAL * NBIN)
                       + (size_t)chunk * CHB * NBIN;
    #pragma unroll
    for (int q = 0; q < 6; ++q) {
        const int o   = tid + (q << 9);              // 0..3071
        const int c   = o / NBIN;                    // 0..62
        const int bin = o - c * NBIN;
        const int i0 = s_yiT[0][bin], i1 = s_yiT[1][bin];
        const int i2 = s_yiT[2][bin], i3 = s_yiT[3][bin];
        const float w0 = s_ywT[0][bin], w1 = s_ywT[1][bin];
        const float w2 = s_ywT[2][bin], w3 = s_ywT[3][bin];
        const float a0 = (w0 * s_G[i0 + c]      + w1 * s_G[i1 + c])
                       + (w2 * s_G[i2 + c]      + w3 * s_G[i3 + c]);
        const float a1 = (w0 * s_G[i0 + c + 64] + w1 * s_G[i1 + c + 64])
                       + (w2 * s_G[i2 + c + 64] + w3 * s_G[i3 + c + 64]);
        __builtin_nontemporal_store(a0, obase + o);
        __builtin_nontemporal_store(a1, obase + o + 3136);
    }
    if (tid < 64) {                                  // tail: o = 3072..3135
        const int o   = tid + 3072;
        const int c   = o / NBIN;                    // 62..63
        const int bin = o - c * NBIN;
        const int i0 = s_yiT[0][bin], i1 = s_yiT[1][bin];
        const int i2 = s_yiT[2][bin], i3 = s_yiT[3][bin];
        const float w0 = s_ywT[0][bin], w1 = s_ywT[1][bin];
        const float w2 = s_ywT[2][bin], w3 = s_ywT[3][bin];
        const float a0 = (w0 * s_G[i0 + c]      + w1 * s_G[i1 + c])
                       + (w2 * s_G[i2 + c]      + w3 * s_G[i3 + c]);
        const float a1 = (w0 * s_G[i0 + c + 64] + w1 * s_G[i1 + c + 64])
                       + (w2 * s_G[i2 + c + 64] + w3 * s_G[i3 + c + 64]);
        __builtin_nontemporal_store(a0, obase + o);
        __builtin_nontemporal_store(a1, obase + o + 3136);
    }
}

// ---------------- fallback if workspace too small ----------------
__global__ __launch_bounds__(256) void roi_align_fallback(
    const float* __restrict__ feat,
    const float* __restrict__ rois,
    float* __restrict__ out)
{
    __shared__ float s_w[16][NBIN];
    __shared__ int   s_i[16][NBIN];

    const int blk    = blockIdx.x;
    const int roi_id = blk >> 3;
    const int chunk  = blk & 7;
    const int tid    = threadIdx.x;

    const float* roi = rois + roi_id * 5;

    if (tid < NBIN * 4) {
        const float swx = roi[1] * SCALE;
        const float shy = roi[2] * SCALE;
        const float ewx = roi[3] * SCALE;
        const float ehy = roi[4] * SCALE;
        const float rw = fmaxf(ewx - swx, 1.0f);
        const float rh = fmaxf(ehy - shy, 1.0f);
        const float bw = rw * (1.0f / PW);
        const float bh = rh * (1.0f / PH);

        const int bin = tid >> 2;
        const int s   = tid & 3;
        const int iy  = s >> 1, ix = s & 1;
        const int py  = bin / PW, px = bin % PW;

        const float y = shy + ((float)py + ((float)iy + 0.5f) * 0.5f) * bh;
        const float x = swx + ((float)px + ((float)ix + 0.5f) * 0.5f) * bw;

        const bool vy = (y >= -1.0f) && (y <= (float)H_);
        float yc = fmaxf(y, 0.0f);
        int ylo = (int)floorf(yc);
        int yhi;
        if (ylo >= H_ - 1) { ylo = H_ - 1; yhi = H_ - 1; yc = (float)(H_ - 1); }
        else               { yhi = ylo + 1; }
        const float ly = yc - (float)ylo;
        const float hy = 1.0f - ly;

        const bool vx = (x >= -1.0f) && (x <= (float)W_);
        float xc = fmaxf(x, 0.0f);
        int xlo = (int)floorf(xc);
        int xhi;
        if (xlo >= W_ - 1) { xlo = W_ - 1; xhi = W_ - 1; xc = (float)(W_ - 1); }
        else               { xhi = xlo + 1; }
        const float lx = xc - (float)xlo;
        const float hx = 1.0f - lx;

        const float v = (vy && vx) ? 0.25f : 0.0f;

        const int r = s * 4;
        s_w[r + 0][bin] = hy * hx * v;
        s_w[r + 1][bin] = hy * lx * v;
        s_w[r + 2][bin] = ly * hx * v;
        s_w[r + 3][bin] = ly * lx * v;
        s_i[r + 0][bin] = ylo * W_ + xlo;
        s_i[r + 1][bin] = ylo * W_ + xhi;
        s_i[r + 2][bin] = yhi * W_ + xlo;
        s_i[r + 3][bin] = yhi * W_ + xhi;
    }
    __syncthreads();

    const float* fbase = feat + (size_t)chunk * 128 * HW_TOTAL;
    float* obase = out + (size_t)roi_id * (C_TOTAL * NBIN)
                       + (size_t)chunk * 128 * NBIN;

    for (int o = tid; o < 128 * NBIN; o += 256) {
        const int c   = o / NBIN;
        const int bin = o - c * NBIN;
        const float* f = fbase + c * HW_TOTAL;
        float acc = 0.0f;
        #pragma unroll
        for (int r = 0; r < 16; ++r) acc += s_w[r][bin] * f[s_i[r][bin]];
        obase[o] = acc;
    }
}

extern "C" void kernel_launch(void* const* d_in, const int* in_sizes, int n_in,
                              void* d_out, int out_size, void* d_ws, size_t ws_size,
                              hipStream_t stream) {
    const float* feat = (const float*)d_in[0];
    const float* rois = (const float*)d_in[1];
    float* out = (float*)d_out;

    const size_t need = (size_t)HW_TOTAL * C_TOTAL * sizeof(float);  // 10.24 MB
    if (ws_size >= need) {
        float* featT = (float*)d_ws;
        transpose_kernel<<<dim3(40 * (C_TOTAL / 64)), dim3(256), 0, stream>>>(feat, featT);
        roi_sep_kernel<<<dim3(NROIS * NCHUNK), dim3(512), 0, stream>>>(featT, rois, out);
    } else {
        roi_align_fallback<<<dim3(NROIS * 8), dim3(256), 0, stream>>>(feat, rois, out);
    }
}

// Round 8
// 59.845 us; speedup vs baseline: 1.2212x; 1.2212x over previous
//
#include <hip/hip_runtime.h>

#define PH 7
#define PW 7
#define SCALE 0.0625f
#define C_TOTAL 1024
#define H_ 50
#define W_ 50
#define HW_TOTAL (H_ * W_)                  // 2500
#define NROIS 512
#define NBIN (PH * PW)                      // 49
#define CHB 64                              // channels per block
#define NCHUNK (C_TOTAL / CHB)              // 16
#define ROWB (W_ * C_TOTAL * 4)             // featT row stride bytes (204800)
#define COLB (C_TOTAL * 4)                  // featT col stride bytes (4096)
#define RMAX 17                             // max distinct rows per ROI (bh<=16/7 -> R<=17, clamped)
#define GP   66                             // padded channel pitch of s_G (EVEN -> 8B-aligned float2 reads)

// ---------------- transpose: feat [C, HW] -> featT [HW, C] ----------------
__global__ __launch_bounds__(256) void transpose_kernel(
    const float* __restrict__ feat, float* __restrict__ featT)
{
    __shared__ float tile[64][65];
    const int hw0 = (blockIdx.x % 40) * 64;
    const int c0  = (blockIdx.x / 40) * 64;
    const int tx = threadIdx.x & 63;
    const int ty = threadIdx.x >> 6;        // 0..3

    const int hw_r = hw0 + tx;
    if (hw_r < HW_TOTAL) {
        #pragma unroll
        for (int j = 0; j < 16; ++j) {
            const int c_l = j * 4 + ty;
            tile[c_l][tx] = feat[(size_t)(c0 + c_l) * HW_TOTAL + hw_r];
        }
    }
    __syncthreads();
    #pragma unroll
    for (int j = 0; j < 16; ++j) {
        const int hw_l = j * 4 + ty;
        const int hw = hw0 + hw_l;
        if (hw < HW_TOTAL)
            featT[(size_t)hw * C_TOTAL + c0 + tx] = tile[tx][hw_l];
    }
}

// uniform SGPR base + VGPR byte offset -> saddr+voffset global_load
__device__ __forceinline__ float ldf(const char* base, unsigned byte_off) {
    return *reinterpret_cast<const float*>(base + byte_off);
}

// ---------------- main: separable two-phase ROI-align ----------------
// out[py][px] = sum_j WY_j * G[row_j][px],  G[r][px] = sum_i WX_i * F[r, x_i]
// R8: phase 1 is EXACTLY R4 (best measured: 24-32 waves/CU, 28-load
// straight-line batch, VGPR 84 -- R7's Little's-law check confirmed phase 1
// is at the in-flight-bytes maximum). The remaining big term is phase 2's
// LDS-pipe time (~400 scattered b32 ds_read wave-instrs/block + 4.7M
// conflict cycles). Fix: each thread-iter serves 4 outputs -- channels
// (2c2, 2c2+1, 2c2+32, 2c2+33) of one bin -- via 8 x ds_read_b64 (float2,
// GP=66 for 8B alignment) + 8 table reads = 16 ds instrs / 4 outputs,
// a 2x cut vs 16/2; table + index VALU amortizes 2x too.
__global__ __launch_bounds__(512, 6) void roi_sep_kernel(
    const float* __restrict__ featT,
    const float* __restrict__ rois,
    float* __restrict__ out)
{
    __shared__ __align__(16) float s_G[RMAX * 7 * GP];  // 31416 B [slot][px][ch(pad66)]
    __shared__ __align__(16) int   s_xoff[7][4];        // col byte offsets (compacted)
    __shared__ __align__(16) float s_xw[7][4];
    __shared__ __align__(16) int   s_yiT[4][NBIN];      // transposed: elem index into s_G
    __shared__ __align__(16) float s_ywT[4][NBIN];      // transposed: y-tap weights

    const int blk    = blockIdx.x;
    const int roi_id = blk >> 4;             // / NCHUNK
    const int chunk  = blk & (NCHUNK - 1);
    const int tid    = threadIdx.x;

    const float* roi = rois + roi_id * 5;

    // row range (uniform scalar math, recomputed identically by all threads)
    const float shy = roi[2] * SCALE, ehy = roi[4] * SCALE;
    const float rht = fmaxf(ehy - shy, 1.0f);
    const float bh  = rht * (1.0f / 7.0f);
    int r0 = (int)floorf(fmaxf(shy + 0.25f * bh, 0.0f));
    if (r0 > H_ - 1) r0 = H_ - 1;
    const int lol = (int)floorf(fmaxf(shy + 6.75f * bh, 0.0f));
    int r1 = (lol >= H_ - 1) ? (H_ - 1) : (lol + 1);
    if (r1 - r0 + 1 > RMAX) r1 = r0 + RMAX - 1;   // corruption guard (never fires: bh<=16/7)
    const int R  = r1 - r0 + 1;              // <= 17

    // ---- x tables: 7 threads, merge+compact 2 samples -> 4 padded slots ----
    if (tid < 7) {
        const float swx = roi[1] * SCALE, ewx = roi[3] * SCALE;
        const float rwd = fmaxf(ewx - swx, 1.0f);
        const float bw  = rwd * (1.0f / 7.0f);
        const float base = swx + (float)tid * bw;
        const float v0 = base + 0.25f * bw;
        const float v1 = base + 0.75f * bw;

        int lo0, hi0, lo1, hi1;
        float l0, h0, l1, h1, m0, m1;
        {
            const bool val = (v0 >= -1.0f) && (v0 <= (float)W_);
            float vc = fmaxf(v0, 0.0f);
            int lo = (int)floorf(vc);
            if (lo >= W_ - 1) { lo0 = W_ - 1; hi0 = W_ - 1; vc = (float)(W_ - 1); }
            else              { lo0 = lo; hi0 = lo + 1; }
            l0 = vc - (float)lo0; h0 = 1.0f - l0;
            m0 = val ? 1.0f : 0.0f;
        }
        {
            const bool val = (v1 >= -1.0f) && (v1 <= (float)W_);
            float vc = fmaxf(v1, 0.0f);
            int lo = (int)floorf(vc);
            if (lo >= W_ - 1) { lo1 = W_ - 1; hi1 = W_ - 1; vc = (float)(W_ - 1); }
            else              { lo1 = lo; hi1 = lo + 1; }
            l1 = vc - (float)lo1; h1 = 1.0f - l1;
            m1 = val ? 1.0f : 0.0f;
        }

        float W0 = h0 * m0, W1 = l0 * m0, W2 = h1 * m1, W3 = l1 * m1;
        int I0 = lo0, I1 = hi0, I2 = lo1, I3 = hi1;
        if (I1 == I0) { W0 += W1; W1 = 0.0f; }
        if (I2 == I0) { W0 += W2; W2 = 0.0f; }
        else if (I2 == I1) { W1 += W2; W2 = 0.0f; }
        if (I3 == I0) { W0 += W3; W3 = 0.0f; }
        else if (I3 == I1) { W1 += W3; W3 = 0.0f; }
        else if (I3 == I2) { W2 += W3; W3 = 0.0f; }

        // compact zeros right (static swaps). Padded slots keep real in-range
        // indices (duplicates of live entries) with weight 0 -> same-line loads.
        #define CSH(A, B) if (W##A == 0.0f && W##B != 0.0f) { W##A = W##B; I##A = I##B; W##B = 0.0f; }
        CSH(0,1) CSH(1,2) CSH(2,3)
        CSH(0,1) CSH(1,2) CSH(2,3)
        CSH(0,1) CSH(1,2) CSH(2,3)
        #undef CSH

        s_xoff[tid][0] = I0 * COLB; s_xoff[tid][1] = I1 * COLB;
        s_xoff[tid][2] = I2 * COLB; s_xoff[tid][3] = I3 * COLB;
        s_xw[tid][0] = W0; s_xw[tid][1] = W1; s_xw[tid][2] = W2; s_xw[tid][3] = W3;
    }

    // ---- y tables: 49 threads (tid 64..112), one per bin ----
    if (tid >= 64 && tid < 64 + NBIN) {
        const int bin = tid - 64;
        const int py  = bin / 7, px = bin - py * 7;
        const float base = shy + (float)py * bh;
        const float v0 = base + 0.25f * bh;
        const float v1 = base + 0.75f * bh;

        int lo0, hi0, lo1, hi1;
        float l0, h0, l1, h1, m0, m1;
        {
            const bool val = (v0 >= -1.0f) && (v0 <= (float)H_);
            float vc = fmaxf(v0, 0.0f);
            int lo = (int)floorf(vc);
            if (lo >= H_ - 1) { lo0 = H_ - 1; hi0 = H_ - 1; vc = (float)(H_ - 1); }
            else              { lo0 = lo; hi0 = lo + 1; }
            l0 = vc - (float)lo0; h0 = 1.0f - l0;
            m0 = val ? 0.25f : 0.0f;                     // fold mask + /4 mean
        }
        {
            const bool val = (v1 >= -1.0f) && (v1 <= (float)H_);
            float vc = fmaxf(v1, 0.0f);
            int lo = (int)floorf(vc);
            if (lo >= H_ - 1) { lo1 = H_ - 1; hi1 = H_ - 1; vc = (float)(H_ - 1); }
            else              { lo1 = lo; hi1 = lo + 1; }
            l1 = vc - (float)lo1; h1 = 1.0f - l1;
            m1 = val ? 0.25f : 0.0f;
        }

        // slot clamp matches the (never-firing) R clamp above
        const int s0 = min(lo0 - r0, RMAX - 1), s1 = min(hi0 - r0, RMAX - 1);
        const int s2 = min(lo1 - r0, RMAX - 1), s3 = min(hi1 - r0, RMAX - 1);
        s_yiT[0][bin] = (s0 * 7 + px) * GP;
        s_yiT[1][bin] = (s1 * 7 + px) * GP;
        s_yiT[2][bin] = (s2 * 7 + px) * GP;
        s_yiT[3][bin] = (s3 * 7 + px) * GP;
        s_ywT[0][bin] = h0 * m0; s_ywT[1][bin] = l0 * m0;
        s_ywT[2][bin] = h1 * m1; s_ywT[3][bin] = l1 * m1;
    }
    __syncthreads();

    // ---- hoist x tables into SGPRs (wave-uniform; 0 VGPR cost) ----
    int   xo_s[7][4];
    float xw_s[7][4];
    #pragma unroll
    for (int i = 0; i < 7; ++i) {
        const int4   t = *(const int4*)  s_xoff[i];
        const float4 w = *(const float4*)s_xw[i];
        xo_s[i][0] = __builtin_amdgcn_readfirstlane(t.x);
        xo_s[i][1] = __builtin_amdgcn_readfirstlane(t.y);
        xo_s[i][2] = __builtin_amdgcn_readfirstlane(t.z);
        xo_s[i][3] = __builtin_amdgcn_readfirstlane(t.w);
        xw_s[i][0] = __uint_as_float(__builtin_amdgcn_readfirstlane(__float_as_uint(w.x)));
        xw_s[i][1] = __uint_as_float(__builtin_amdgcn_readfirstlane(__float_as_uint(w.y)));
        xw_s[i][2] = __uint_as_float(__builtin_amdgcn_readfirstlane(__float_as_uint(w.z)));
        xw_s[i][3] = __uint_as_float(__builtin_amdgcn_readfirstlane(__float_as_uint(w.w)));
    }

    // ---- phase 1: G[row][px][ch] -- row-based, 28 batched loads per row ----
    // (EXACT R4 structure: deep straight-line batch + fence; VGPR must stay
    //  high enough to hold f[7][4] -- tripwire VGPR_Count >= 60)
    const int wave = tid >> 6, lane = tid & 63;
    const char* fb  = (const char*)featT;
    const int laneB = (chunk * CHB + lane) * 4;

    for (int rs = wave; rs < R; rs += 8) {
        const unsigned rb = (unsigned)(laneB + (r0 + rs) * ROWB);
        float f[7][4];
        #pragma unroll
        for (int px = 0; px < 7; ++px) {
            f[px][0] = ldf(fb + xo_s[px][0], rb);
            f[px][1] = ldf(fb + xo_s[px][1], rb);
            f[px][2] = ldf(fb + xo_s[px][2], rb);
            f[px][3] = ldf(fb + xo_s[px][3], rb);
        }
        // fence: compiler may not sink loads below this point -> all 28 issue
        // before the first use (28-deep MLP preserved)
        __asm__ __volatile__("" ::: "memory");
        float* gbase = &s_G[rs * 7 * GP + lane];
        #pragma unroll
        for (int px = 0; px < 7; ++px) {
            gbase[px * GP] = (xw_s[px][0] * f[px][0] + xw_s[px][1] * f[px][1])
                           + (xw_s[px][2] * f[px][2] + xw_s[px][3] * f[px][3]);
        }
    }
    __syncthreads();

    // ---- phase 2 (fused store): thread-iter serves 4 outputs of one bin:
    // channels (2c2, 2c2+1, 2c2+32, 2c2+33). G reads are float2 (b64, GP
    // even -> aligned); tables amortized over 4 outputs. Stores piecewise
    // lane-linear (49-element runs). 16 ds instrs / 4 outputs (was 16/2).
    float* obase = out + (size_t)roi_id * (C_TOTAL * NBIN)
                       + (size_t)chunk * CHB * NBIN;
    for (int p = tid; p < 16 * NBIN; p += 512) {       // 784 = 512 + 272
        const int c2  = p / NBIN;                      // 0..15
        const int bin = p - c2 * NBIN;
        const int cA  = c2 * 2;                        // 0,2,..,30
        const int cB  = cA + 32;                       // 32,..,62
        const int i0 = s_yiT[0][bin], i1 = s_yiT[1][bin];
        const int i2 = s_yiT[2][bin], i3 = s_yiT[3][bin];
        const float w0 = s_ywT[0][bin], w1 = s_ywT[1][bin];
        const float w2 = s_ywT[2][bin], w3 = s_ywT[3][bin];

        const float2 a0 = *(const float2*)&s_G[i0 + cA];
        const float2 a1 = *(const float2*)&s_G[i1 + cA];
        const float2 a2 = *(const float2*)&s_G[i2 + cA];
        const float2 a3 = *(const float2*)&s_G[i3 + cA];
        const float2 b0 = *(const float2*)&s_G[i0 + cB];
        const float2 b1 = *(const float2*)&s_G[i1 + cB];
        const float2 b2 = *(const float2*)&s_G[i2 + cB];
        const float2 b3 = *(const float2*)&s_G[i3 + cB];

        const float oA0 = (w0 * a0.x + w1 * a1.x) + (w2 * a2.x + w3 * a3.x);
        const float oA1 = (w0 * a0.y + w1 * a1.y) + (w2 * a2.y + w3 * a3.y);
        const float oB0 = (w0 * b0.x + w1 * b1.x) + (w2 * b2.x + w3 * b3.x);
        const float oB1 = (w0 * b0.y + w1 * b1.y) + (w2 * b2.y + w3 * b3.y);

        const int oA = cA * NBIN + bin;                // out[(cA)][bin]
        __builtin_nontemporal_store(oA0, obase + oA);
        __builtin_nontemporal_store(oA1, obase + oA + NBIN);
        __builtin_nontemporal_store(oB0, obase + oA + 32 * NBIN);
        __builtin_nontemporal_store(oB1, obase + oA + 33 * NBIN);
    }
}

// ---------------- fallback if workspace too small ----------------
__global__ __launch_bounds__(256) void roi_align_fallback(
    const float* __restrict__ feat,
    const float* __restrict__ rois,
    float* __restrict__ out)
{
    __shared__ float s_w[16][NBIN];
    __shared__ int   s_i[16][NBIN];

    const int blk    = blockIdx.x;
    const int roi_id = blk >> 3;
    const int chunk  = blk & 7;
    const int tid    = threadIdx.x;

    const float* roi = rois + roi_id * 5;

    if (tid < NBIN * 4) {
        const float swx = roi[1] * SCALE;
        const float shy = roi[2] * SCALE;
        const float ewx = roi[3] * SCALE;
        const float ehy = roi[4] * SCALE;
        const float rw = fmaxf(ewx - swx, 1.0f);
        const float rh = fmaxf(ehy - shy, 1.0f);
        const float bw = rw * (1.0f / PW);
        const float bh = rh * (1.0f / PH);

        const int bin = tid >> 2;
        const int s   = tid & 3;
        const int iy  = s >> 1, ix = s & 1;
        const int py  = bin / PW, px = bin % PW;

        const float y = shy + ((float)py + ((float)iy + 0.5f) * 0.5f) * bh;
        const float x = swx + ((float)px + ((float)ix + 0.5f) * 0.5f) * bw;

        const bool vy = (y >= -1.0f) && (y <= (float)H_);
        float yc = fmaxf(y, 0.0f);
        int ylo = (int)floorf(yc);
        int yhi;
        if (ylo >= H_ - 1) { ylo = H_ - 1; yhi = H_ - 1; yc = (float)(H_ - 1); }
        else               { yhi = ylo + 1; }
        const float ly = yc - (float)ylo;
        const float hy = 1.0f - ly;

        const bool vx = (x >= -1.0f) && (x <= (float)W_);
        float xc = fmaxf(x, 0.0f);
        int xlo = (int)floorf(xc);
        int xhi;
        if (xlo >= W_ - 1) { xlo = W_ - 1; xhi = W_ - 1; xc = (float)(W_ - 1); }
        else               { xhi = xlo + 1; }
        const float lx = xc - (float)xlo;
        const float hx = 1.0f - lx;

        const float v = (vy && vx) ? 0.25f : 0.0f;

        const int r = s * 4;
        s_w[r + 0][bin] = hy * hx * v;
        s_w[r + 1][bin] = hy * lx * v;
        s_w[r + 2][bin] = ly * hx * v;
        s_w[r + 3][bin] = ly * lx * v;
        s_i[r + 0][bin] = ylo * W_ + xlo;
        s_i[r + 1][bin] = ylo * W_ + xhi;
        s_i[r + 2][bin] = yhi * W_ + xlo;
        s_i[r + 3][bin] = yhi * W_ + xhi;
    }
    __syncthreads();

    const float* fbase = feat + (size_t)chunk * 128 * HW_TOTAL;
    float* obase = out + (size_t)roi_id * (C_TOTAL * NBIN)
                       + (size_t)chunk * 128 * NBIN;

    for (int o = tid; o < 128 * NBIN; o += 256) {
        const int c   = o / NBIN;
        const int bin = o - c * NBIN;
        const float* f = fbase + c * HW_TOTAL;
        float acc = 0.0f;
        #pragma unroll
        for (int r = 0; r < 16; ++r) acc += s_w[r][bin] * f[s_i[r][bin]];
        obase[o] = acc;
    }
}

extern "C" void kernel_launch(void* const* d_in, const int* in_sizes, int n_in,
                              void* d_out, int out_size, void* d_ws, size_t ws_size,
                              hipStream_t stream) {
    const float* feat = (const float*)d_in[0];
    const float* rois = (const float*)d_in[1];
    float* out = (float*)d_out;

    const size_t need = (size_t)HW_TOTAL * C_TOTAL * sizeof(float);  // 10.24 MB
    if (ws_size >= need) {
        float* featT = (float*)d_ws;
        transpose_kernel<<<dim3(40 * (C_TOTAL / 64)), dim3(256), 0, stream>>>(feat, featT);
        roi_sep_kernel<<<dim3(NROIS * NCHUNK), dim3(512), 0, stream>>>(featT, rois, out);
    } else {
        roi_align_fallback<<<dim3(NROIS * 8), dim3(256), 0, stream>>>(feat, rois, out);
    }
}

// Round 9
// 48.274 us; speedup vs baseline: 1.5139x; 1.2397x over previous
//
#include <hip/hip_runtime.h>

#define PH 7
#define PW 7
#define SCALE 0.0625f
#define C_TOTAL 1024
#define H_ 50
#define W_ 50
#define HW_TOTAL (H_ * W_)                  // 2500
#define NROIS 512
#define NBIN (PH * PW)                      // 49
#define CHB 64                              // channels per block
#define NCHUNK (C_TOTAL / CHB)              // 16
#define ROWB (W_ * C_TOTAL * 4)             // featT row stride bytes (204800)
#define COLB (C_TOTAL * 4)                  // featT col stride bytes (4096)
#define RMAX 17                             // max distinct rows per ROI (bh<=16/7 -> R<=17, clamped)
#define GP   65                             // padded channel pitch of s_G (R4 value)

// per-ROI table block (float units): [0..27]=xoff(int) [32..59]=xw
// [64..259]=yiT(int, t*49+bin) [260..455]=ywT [456]=r0 [457]=R
#define TBL_OFF    (HW_TOTAL * C_TOTAL)     // floats
#define TBL_STRIDE 512                      // floats per roi (2 KB)

// ---------------- transpose + per-ROI table precompute ----------------
__global__ __launch_bounds__(256) void transpose_kernel(
    const float* __restrict__ feat, float* __restrict__ featT,
    const float* __restrict__ rois)
{
    __shared__ float tile[64][65];
    const int hw0 = (blockIdx.x % 40) * 64;
    const int c0  = (blockIdx.x / 40) * 64;
    const int tx = threadIdx.x & 63;
    const int ty = threadIdx.x >> 6;        // 0..3

    const int hw_r = hw0 + tx;
    if (hw_r < HW_TOTAL) {
        #pragma unroll
        for (int j = 0; j < 16; ++j) {
            const int c_l = j * 4 + ty;
            tile[c_l][tx] = feat[(size_t)(c0 + c_l) * HW_TOTAL + hw_r];
        }
    }
    __syncthreads();
    #pragma unroll
    for (int j = 0; j < 16; ++j) {
        const int hw_l = j * 4 + ty;
        const int hw = hw0 + hw_l;
        if (hw < HW_TOTAL)
            featT[(size_t)hw * C_TOTAL + c0 + tx] = tile[tx][hw_l];
    }

    // ---- table precompute: blocks 0..511 handle roi = blockIdx.x ----
    // (independent of the tile work above; no barrier needed)
    const int roi_id = blockIdx.x;
    if (roi_id >= NROIS) return;
    const float* roi = rois + roi_id * 5;
    float* tbl  = featT + TBL_OFF + (size_t)roi_id * TBL_STRIDE;
    int*   tbli = (int*)tbl;
    const int tid = threadIdx.x;

    // uniform row-range math (same as the old in-kernel version)
    const float shy = roi[2] * SCALE, ehy = roi[4] * SCALE;
    const float rht = fmaxf(ehy - shy, 1.0f);
    const float bh  = rht * (1.0f / 7.0f);
    int r0 = (int)floorf(fmaxf(shy + 0.25f * bh, 0.0f));
    if (r0 > H_ - 1) r0 = H_ - 1;
    const int lol = (int)floorf(fmaxf(shy + 6.75f * bh, 0.0f));
    int r1 = (lol >= H_ - 1) ? (H_ - 1) : (lol + 1);
    if (r1 - r0 + 1 > RMAX) r1 = r0 + RMAX - 1;   // guard (never fires: bh<=16/7)
    const int R  = r1 - r0 + 1;

    if (tid == 128) { tbli[456] = r0; tbli[457] = R; }

    if (tid < 7) {
        const float swx = roi[1] * SCALE, ewx = roi[3] * SCALE;
        const float rwd = fmaxf(ewx - swx, 1.0f);
        const float bw  = rwd * (1.0f / 7.0f);
        const float base = swx + (float)tid * bw;
        const float v0 = base + 0.25f * bw;
        const float v1 = base + 0.75f * bw;

        int lo0, hi0, lo1, hi1;
        float l0, h0, l1, h1, m0, m1;
        {
            const bool val = (v0 >= -1.0f) && (v0 <= (float)W_);
            float vc = fmaxf(v0, 0.0f);
            int lo = (int)floorf(vc);
            if (lo >= W_ - 1) { lo0 = W_ - 1; hi0 = W_ - 1; vc = (float)(W_ - 1); }
            else              { lo0 = lo; hi0 = lo + 1; }
            l0 = vc - (float)lo0; h0 = 1.0f - l0;
            m0 = val ? 1.0f : 0.0f;
        }
        {
            const bool val = (v1 >= -1.0f) && (v1 <= (float)W_);
            float vc = fmaxf(v1, 0.0f);
            int lo = (int)floorf(vc);
            if (lo >= W_ - 1) { lo1 = W_ - 1; hi1 = W_ - 1; vc = (float)(W_ - 1); }
            else              { lo1 = lo; hi1 = lo + 1; }
            l1 = vc - (float)lo1; h1 = 1.0f - l1;
            m1 = val ? 1.0f : 0.0f;
        }

        float W0 = h0 * m0, W1 = l0 * m0, W2 = h1 * m1, W3 = l1 * m1;
        int I0 = lo0, I1 = hi0, I2 = lo1, I3 = hi1;
        if (I1 == I0) { W0 += W1; W1 = 0.0f; }
        if (I2 == I0) { W0 += W2; W2 = 0.0f; }
        else if (I2 == I1) { W1 += W2; W2 = 0.0f; }
        if (I3 == I0) { W0 += W3; W3 = 0.0f; }
        else if (I3 == I1) { W1 += W3; W3 = 0.0f; }
        else if (I3 == I2) { W2 += W3; W3 = 0.0f; }

        #define CSH(A, B) if (W##A == 0.0f && W##B != 0.0f) { W##A = W##B; I##A = I##B; W##B = 0.0f; }
        CSH(0,1) CSH(1,2) CSH(2,3)
        CSH(0,1) CSH(1,2) CSH(2,3)
        CSH(0,1) CSH(1,2) CSH(2,3)
        #undef CSH

        tbli[tid * 4 + 0] = I0 * COLB; tbli[tid * 4 + 1] = I1 * COLB;
        tbli[tid * 4 + 2] = I2 * COLB; tbli[tid * 4 + 3] = I3 * COLB;
        tbl[32 + tid * 4 + 0] = W0; tbl[32 + tid * 4 + 1] = W1;
        tbl[32 + tid * 4 + 2] = W2; tbl[32 + tid * 4 + 3] = W3;
    }

    if (tid >= 64 && tid < 64 + NBIN) {
        const int bin = tid - 64;
        const int py  = bin / 7, px = bin - py * 7;
        const float base = shy + (float)py * bh;
        const float v0 = base + 0.25f * bh;
        const float v1 = base + 0.75f * bh;

        int lo0, hi0, lo1, hi1;
        float l0, h0, l1, h1, m0, m1;
        {
            const bool val = (v0 >= -1.0f) && (v0 <= (float)H_);
            float vc = fmaxf(v0, 0.0f);
            int lo = (int)floorf(vc);
            if (lo >= H_ - 1) { lo0 = H_ - 1; hi0 = H_ - 1; vc = (float)(H_ - 1); }
            else              { lo0 = lo; hi0 = lo + 1; }
            l0 = vc - (float)lo0; h0 = 1.0f - l0;
            m0 = val ? 0.25f : 0.0f;                     // fold mask + /4 mean
        }
        {
            const bool val = (v1 >= -1.0f) && (v1 <= (float)H_);
            float vc = fmaxf(v1, 0.0f);
            int lo = (int)floorf(vc);
            if (lo >= H_ - 1) { lo1 = H_ - 1; hi1 = H_ - 1; vc = (float)(H_ - 1); }
            else              { lo1 = lo; hi1 = lo + 1; }
            l1 = vc - (float)lo1; h1 = 1.0f - l1;
            m1 = val ? 0.25f : 0.0f;
        }

        const int s0 = min(lo0 - r0, RMAX - 1), s1 = min(hi0 - r0, RMAX - 1);
        const int s2 = min(lo1 - r0, RMAX - 1), s3 = min(hi1 - r0, RMAX - 1);
        tbli[64 + 0 * NBIN + bin] = (s0 * 7 + px) * GP;
        tbli[64 + 1 * NBIN + bin] = (s1 * 7 + px) * GP;
        tbli[64 + 2 * NBIN + bin] = (s2 * 7 + px) * GP;
        tbli[64 + 3 * NBIN + bin] = (s3 * 7 + px) * GP;
        tbl[260 + 0 * NBIN + bin] = h0 * m0; tbl[260 + 1 * NBIN + bin] = l0 * m0;
        tbl[260 + 2 * NBIN + bin] = h1 * m1; tbl[260 + 3 * NBIN + bin] = l1 * m1;
    }
}

// uniform SGPR base + VGPR byte offset -> saddr+voffset global_load
__device__ __forceinline__ float ldf(const char* base, unsigned byte_off) {
    return *reinterpret_cast<const float*>(base + byte_off);
}

// ---------------- main: separable two-phase ROI-align ----------------
// R9: phases 1 & 2 are EXACT R4 (best measured 54.6). Only the prologue
// changed: per-ROI tables are PRECOMPUTED (transpose kernel) -> prologue is
// 2 scalar loads + 14 uniform table loads (SGPR-hoisted) + one 392-float
// LDS stage. The pre-phase-1 barrier is DELETED: phase 1 reads no LDS
// tables, so the single post-phase-1 barrier covers s_G AND s_ytbl.
// Waves issue the 28-load batches almost at kernel entry.
__global__ __launch_bounds__(512, 6) void roi_sep_kernel(
    const float* __restrict__ featT,
    float* __restrict__ out)
{
    __shared__ __align__(16) float s_G[RMAX * 7 * GP];  // 30940 B [slot][px][ch(pad65)]
    __shared__ __align__(16) float s_ytbl[392];         // yiT(int)[196] ++ ywT[196]

    const int blk    = blockIdx.x;
    const int roi_id = blk >> 4;             // / NCHUNK
    const int chunk  = blk & (NCHUNK - 1);
    const int tid    = threadIdx.x;

    const float* tbl  = featT + TBL_OFF + (size_t)roi_id * TBL_STRIDE;
    const int*   tbli = (const int*)tbl;

    // stage y tables (single coalesced load + ds_write; consumed after the
    // post-phase-1 barrier)
    if (tid < 392) s_ytbl[tid] = tbl[64 + tid];

    const int r0 = __builtin_amdgcn_readfirstlane(tbli[456]);
    const int R  = __builtin_amdgcn_readfirstlane(tbli[457]);

    // x tables -> SGPRs (uniform address loads; rfl pins them scalar)
    int   xo_s[7][4];
    float xw_s[7][4];
    #pragma unroll
    for (int i = 0; i < 7; ++i) {
        const int4   t = ((const int4*)tbli)[i];
        const float4 w = ((const float4*)tbl)[8 + i];
        xo_s[i][0] = __builtin_amdgcn_readfirstlane(t.x);
        xo_s[i][1] = __builtin_amdgcn_readfirstlane(t.y);
        xo_s[i][2] = __builtin_amdgcn_readfirstlane(t.z);
        xo_s[i][3] = __builtin_amdgcn_readfirstlane(t.w);
        xw_s[i][0] = __uint_as_float(__builtin_amdgcn_readfirstlane(__float_as_uint(w.x)));
        xw_s[i][1] = __uint_as_float(__builtin_amdgcn_readfirstlane(__float_as_uint(w.y)));
        xw_s[i][2] = __uint_as_float(__builtin_amdgcn_readfirstlane(__float_as_uint(w.z)));
        xw_s[i][3] = __uint_as_float(__builtin_amdgcn_readfirstlane(__float_as_uint(w.w)));
    }

    // ---- phase 1: EXACT R4 -- row-based, 28 batched loads per row ----
    const int wave = tid >> 6, lane = tid & 63;
    const char* fb  = (const char*)featT;
    const int laneB = (chunk * CHB + lane) * 4;

    for (int rs = wave; rs < R; rs += 8) {
        const unsigned rb = (unsigned)(laneB + (r0 + rs) * ROWB);
        float f[7][4];
        #pragma unroll
        for (int px = 0; px < 7; ++px) {
            f[px][0] = ldf(fb + xo_s[px][0], rb);
            f[px][1] = ldf(fb + xo_s[px][1], rb);
            f[px][2] = ldf(fb + xo_s[px][2], rb);
            f[px][3] = ldf(fb + xo_s[px][3], rb);
        }
        // fence: compiler may not sink loads below this point -> all 28 issue
        // before the first use (28-deep MLP preserved)
        __asm__ __volatile__("" ::: "memory");
        float* gbase = &s_G[rs * 7 * GP + lane];
        #pragma unroll
        for (int px = 0; px < 7; ++px) {
            gbase[px * GP] = (xw_s[px][0] * f[px][0] + xw_s[px][1] * f[px][1])
                           + (xw_s[px][2] * f[px][2] + xw_s[px][3] * f[px][3]);
        }
    }
    __syncthreads();   // the ONE barrier: covers s_G and s_ytbl

    // ---- phase 2: EXACT R4 -- thread handles o and o+1568 (same bin,
    // channels c and c+32); lane-linear nontemporal stores ----
    const int* s_yi = (const int*)s_ytbl;        // [t*49+bin]
    const float* s_yw = s_ytbl + 196;            // [t*49+bin]
    float* obase = out + (size_t)roi_id * (C_TOTAL * NBIN)
                       + (size_t)chunk * CHB * NBIN;
    #pragma unroll
    for (int q = 0; q < 3; ++q) {
        const int o   = tid + (q << 9);              // 0..1535
        const int c   = o / NBIN;                    // 0..31
        const int bin = o - c * NBIN;
        const int i0 = s_yi[0 * NBIN + bin], i1 = s_yi[1 * NBIN + bin];
        const int i2 = s_yi[2 * NBIN + bin], i3 = s_yi[3 * NBIN + bin];
        const float w0 = s_yw[0 * NBIN + bin], w1 = s_yw[1 * NBIN + bin];
        const float w2 = s_yw[2 * NBIN + bin], w3 = s_yw[3 * NBIN + bin];
        const float a0 = (w0 * s_G[i0 + c]      + w1 * s_G[i1 + c])
                       + (w2 * s_G[i2 + c]      + w3 * s_G[i3 + c]);
        const float a1 = (w0 * s_G[i0 + c + 32] + w1 * s_G[i1 + c + 32])
                       + (w2 * s_G[i2 + c + 32] + w3 * s_G[i3 + c + 32]);
        __builtin_nontemporal_store(a0, obase + o);
        __builtin_nontemporal_store(a1, obase + o + 1568);
    }
    if (tid < 32) {                                  // tail: o = 1536..1567
        const int o   = tid + 1536;
        const int c   = 31;
        const int bin = o - c * NBIN;
        const int i0 = s_yi[0 * NBIN + bin], i1 = s_yi[1 * NBIN + bin];
        const int i2 = s_yi[2 * NBIN + bin], i3 = s_yi[3 * NBIN + bin];
        const float w0 = s_yw[0 * NBIN + bin], w1 = s_yw[1 * NBIN + bin];
        const float w2 = s_yw[2 * NBIN + bin], w3 = s_yw[3 * NBIN + bin];
        const float a0 = (w0 * s_G[i0 + c]      + w1 * s_G[i1 + c])
                       + (w2 * s_G[i2 + c]      + w3 * s_G[i3 + c]);
        const float a1 = (w0 * s_G[i0 + c + 32] + w1 * s_G[i1 + c + 32])
                       + (w2 * s_G[i2 + c + 32] + w3 * s_G[i3 + c + 32]);
        __builtin_nontemporal_store(a0, obase + o);
        __builtin_nontemporal_store(a1, obase + o + 1568);
    }
}

// ---------------- fallback if workspace too small ----------------
__global__ __launch_bounds__(256) void roi_align_fallback(
    const float* __restrict__ feat,
    const float* __restrict__ rois,
    float* __restrict__ out)
{
    __shared__ float s_w[16][NBIN];
    __shared__ int   s_i[16][NBIN];

    const int blk    = blockIdx.x;
    const int roi_id = blk >> 3;
    const int chunk  = blk & 7;
    const int tid    = threadIdx.x;

    const float* roi = rois + roi_id * 5;

    if (tid < NBIN * 4) {
        const float swx = roi[1] * SCALE;
        const float shy = roi[2] * SCALE;
        const float ewx = roi[3] * SCALE;
        const float ehy = roi[4] * SCALE;
        const float rw = fmaxf(ewx - swx, 1.0f);
        const float rh = fmaxf(ehy - shy, 1.0f);
        const float bw = rw * (1.0f / PW);
        const float bh = rh * (1.0f / PH);

        const int bin = tid >> 2;
        const int s   = tid & 3;
        const int iy  = s >> 1, ix = s & 1;
        const int py  = bin / PW, px = bin % PW;

        const float y = shy + ((float)py + ((float)iy + 0.5f) * 0.5f) * bh;
        const float x = swx + ((float)px + ((float)ix + 0.5f) * 0.5f) * bw;

        const bool vy = (y >= -1.0f) && (y <= (float)H_);
        float yc = fmaxf(y, 0.0f);
        int ylo = (int)floorf(yc);
        int yhi;
        if (ylo >= H_ - 1) { ylo = H_ - 1; yhi = H_ - 1; yc = (float)(H_ - 1); }
        else               { yhi = ylo + 1; }
        const float ly = yc - (float)ylo;
        const float hy = 1.0f - ly;

        const bool vx = (x >= -1.0f) && (x <= (float)W_);
        float xc = fmaxf(x, 0.0f);
        int xlo = (int)floorf(xc);
        int xhi;
        if (xlo >= W_ - 1) { xlo = W_ - 1; xhi = W_ - 1; xc = (float)(W_ - 1); }
        else               { xhi = xlo + 1; }
        const float lx = xc - (float)xlo;
        const float hx = 1.0f - lx;

        const float v = (vy && vx) ? 0.25f : 0.0f;

        const int r = s * 4;
        s_w[r + 0][bin] = hy * hx * v;
        s_w[r + 1][bin] = hy * lx * v;
        s_w[r + 2][bin] = ly * hx * v;
        s_w[r + 3][bin] = ly * lx * v;
        s_i[r + 0][bin] = ylo * W_ + xlo;
        s_i[r + 1][bin] = ylo * W_ + xhi;
        s_i[r + 2][bin] = yhi * W_ + xlo;
        s_i[r + 3][bin] = yhi * W_ + xhi;
    }
    __syncthreads();

    const float* fbase = feat + (size_t)chunk * 128 * HW_TOTAL;
    float* obase = out + (size_t)roi_id * (C_TOTAL * NBIN)
                       + (size_t)chunk * 128 * NBIN;

    for (int o = tid; o < 128 * NBIN; o += 256) {
        const int c   = o / NBIN;
        const int bin = o - c * NBIN;
        const float* f = fbase + c * HW_TOTAL;
        float acc = 0.0f;
        #pragma unroll
        for (int r = 0; r < 16; ++r) acc += s_w[r][bin] * f[s_i[r][bin]];
        obase[o] = acc;
    }
}

extern "C" void kernel_launch(void* const* d_in, const int* in_sizes, int n_in,
                              void* d_out, int out_size, void* d_ws, size_t ws_size,
                              hipStream_t stream) {
    const float* feat = (const float*)d_in[0];
    const float* rois = (const float*)d_in[1];
    float* out = (float*)d_out;

    const size_t need = (size_t)(TBL_OFF + NROIS * TBL_STRIDE) * sizeof(float); // ~11.3 MB
    if (ws_size >= need) {
        float* featT = (float*)d_ws;
        transpose_kernel<<<dim3(40 * (C_TOTAL / 64)), dim3(256), 0, stream>>>(feat, featT, rois);
        roi_sep_kernel<<<dim3(NROIS * NCHUNK), dim3(512), 0, stream>>>(featT, out);
    } else {
        roi_align_fallback<<<dim3(NROIS * 8), dim3(256), 0, stream>>>(feat, rois, out);
    }
}